// Round 11
// baseline (39.614 us; speedup 1.0000x reference)
//
#include <hip/hip_runtime.h>

#define NIN   126
#define NOUT  126
#define KIX   3
#define H     256

// d_ws float offsets (ws is ~256MB; we use ~2.8MB)
#define XE_OFF   0            // [1024][128] scattered x, cols 126/127 = 0
#define W0P_OFF  131072       // [256][128]  W0 padded
#define H1_OFF   163840       // [1024][256]
#define H2_OFF   425984       // [1024][256]
#define TS_OFF   688128       // [1024][128] ts + b2, cols 126/127 = 0

__device__ __forceinline__ float elu1(float v) { return v > 0.f ? v : expm1f(v); }

// ===== k1: scatter x by batch_in_index (4 rows/block) + W0 row pad =====
__global__ __launch_bounds__(512) void k_scatter(
    const float* __restrict__ x, const int* __restrict__ iidx,
    const float* __restrict__ W0, float* __restrict__ ws)
{
    __shared__ float xe[4][128];
    const int t = threadIdx.x, bid = blockIdx.x;
    const int row0 = bid * 4;
    ((float*)xe)[t] = 0.f;                       // 512 = 4*128
    __syncthreads();
    #pragma unroll
    for (int u = 0; u < 3; ++u) {
        const int n = t + u * 512;
        if (n < 4 * NIN * KIX) {
            const int r = n / (NIN * KIX), m = n - r * (NIN * KIX);
            const int j = iidx[(row0 + r) * (NIN * KIX) + m];
            if (j < NIN) atomicAdd(&xe[r][j], x[(row0 + r) * NIN + m / KIX]);
        }
    }
    __syncthreads();
    ws[XE_OFF + row0 * 128 + t] = ((float*)xe)[t];
    // W0 pad: block bid copies output-row bid (126 -> 128, zero tail)
    if (t < 128) ws[W0P_OFF + bid * 128 + t] = (t < NIN) ? W0[bid * NIN + t] : 0.f;
}

// ===== k2: h1 = elu(xe @ W0p^T + b0)  M=1024 N=256 K=128 =====
// grid 256 = 16 row-blocks x 16 neuron-blocks; TPB 256 = 4 waves x 4 neurons
__global__ __launch_bounds__(256) void k_l0(
    const float* __restrict__ ws, const float* __restrict__ b0, float* __restrict__ wso)
{
    __shared__ float4 a4[64 * 32];               // [64 rows][32 f4], XOR-swizzled
    const int t = threadIdx.x;
    const int rb = blockIdx.x & 15, nb = blockIdx.x >> 4;
    const float* src = ws + XE_OFF + rb * 64 * 128;
    #pragma unroll
    for (int p = 0; p < 8; ++p) {                // stage 64x128 f32, coalesced
        const int i4 = p * 256 + t;
        const float4 v = *reinterpret_cast<const float4*>(src + i4 * 4);
        const int row = i4 >> 5, c4 = i4 & 31;
        a4[row * 32 + (c4 ^ (row & 7))] = v;     // G4 XOR swizzle (16B granular)
    }
    __syncthreads();
    const int w = t >> 6, l = t & 63;
    const int ob = __builtin_amdgcn_readfirstlane(nb * 16 + w * 4);
    const float* w0 = ws + W0P_OFF + ob * 128;   // uniform base -> s_load stream
    float acc0 = 0.f, acc1 = 0.f, acc2 = 0.f, acc3 = 0.f;
    #pragma unroll
    for (int kc = 0; kc < 128; kc += 8) {
        const int kq = kc >> 2;
        const float4 v0 = a4[l * 32 + ((kq)     ^ (l & 7))];
        const float4 v1 = a4[l * 32 + ((kq + 1) ^ (l & 7))];
        const float av[8] = {v0.x, v0.y, v0.z, v0.w, v1.x, v1.y, v1.z, v1.w};
        #pragma unroll
        for (int kk = 0; kk < 8; ++kk) {
            acc0 = fmaf(w0[      kc + kk], av[kk], acc0);
            acc1 = fmaf(w0[128 + kc + kk], av[kk], acc1);
            acc2 = fmaf(w0[256 + kc + kk], av[kk], acc2);
            acc3 = fmaf(w0[384 + kc + kk], av[kk], acc3);
        }
    }
    float4 o;
    o.x = elu1(acc0 + b0[ob]);     o.y = elu1(acc1 + b0[ob + 1]);
    o.z = elu1(acc2 + b0[ob + 2]); o.w = elu1(acc3 + b0[ob + 3]);
    *reinterpret_cast<float4*>(wso + H1_OFF + (rb * 64 + l) * 256 + ob) = o;
}

// ===== k3: h2 = elu(h1 @ W1^T + b1)  M=1024 N=256 K=256 =====
__global__ __launch_bounds__(256) void k_l1(
    const float* __restrict__ ws, const float* __restrict__ W1,
    const float* __restrict__ b1, float* __restrict__ wso)
{
    __shared__ float4 a4[64 * 64];               // [64 rows][64 f4], swizzled (64KB)
    const int t = threadIdx.x;
    const int rb = blockIdx.x & 15, nb = blockIdx.x >> 4;
    const float* src = ws + H1_OFF + rb * 64 * 256;
    #pragma unroll
    for (int p = 0; p < 16; ++p) {
        const int i4 = p * 256 + t;
        const float4 v = *reinterpret_cast<const float4*>(src + i4 * 4);
        const int row = i4 >> 6, c4 = i4 & 63;
        a4[row * 64 + (c4 ^ (row & 7))] = v;
    }
    __syncthreads();
    const int w = t >> 6, l = t & 63;
    const int ob = __builtin_amdgcn_readfirstlane(nb * 16 + w * 4);
    const float* w1 = W1 + ob * 256;
    float acc0 = 0.f, acc1 = 0.f, acc2 = 0.f, acc3 = 0.f;
    #pragma unroll
    for (int kc = 0; kc < 256; kc += 8) {
        const int kq = kc >> 2;
        const float4 v0 = a4[l * 64 + ((kq)     ^ (l & 7))];
        const float4 v1 = a4[l * 64 + ((kq + 1) ^ (l & 7))];
        const float av[8] = {v0.x, v0.y, v0.z, v0.w, v1.x, v1.y, v1.z, v1.w};
        #pragma unroll
        for (int kk = 0; kk < 8; ++kk) {
            acc0 = fmaf(w1[      kc + kk], av[kk], acc0);
            acc1 = fmaf(w1[256 + kc + kk], av[kk], acc1);
            acc2 = fmaf(w1[512 + kc + kk], av[kk], acc2);
            acc3 = fmaf(w1[768 + kc + kk], av[kk], acc3);
        }
    }
    float4 o;
    o.x = elu1(acc0 + b1[ob]);     o.y = elu1(acc1 + b1[ob + 1]);
    o.z = elu1(acc2 + b1[ob + 2]); o.w = elu1(acc3 + b1[ob + 3]);
    *reinterpret_cast<float4*>(wso + H2_OFF + (rb * 64 + l) * 256 + ob) = o;
}

// ===== k4: ts = h2 @ W2^T + b2 (cols 126/127 = 0)  M=1024 N=128pad K=256 =====
// grid 256 = 16 rb x 16 nb (8 neurons); TPB 256 = 4 waves x 2 neurons
__global__ __launch_bounds__(256) void k_l2(
    const float* __restrict__ ws, const float* __restrict__ W2,
    const float* __restrict__ b2, float* __restrict__ wso)
{
    __shared__ float4 a4[64 * 64];
    const int t = threadIdx.x;
    const int rb = blockIdx.x & 15, nb = blockIdx.x >> 4;
    const float* src = ws + H2_OFF + rb * 64 * 256;
    #pragma unroll
    for (int p = 0; p < 16; ++p) {
        const int i4 = p * 256 + t;
        const float4 v = *reinterpret_cast<const float4*>(src + i4 * 4);
        const int row = i4 >> 6, c4 = i4 & 63;
        a4[row * 64 + (c4 ^ (row & 7))] = v;
    }
    __syncthreads();
    const int w = t >> 6, l = t & 63;
    const int ob = __builtin_amdgcn_readfirstlane(nb * 8 + w * 2);
    const bool val0 = ob < NOUT, val1 = ob + 1 < NOUT;
    const float* w2a = W2 + (val0 ? ob     : 0) * 256;
    const float* w2b = W2 + (val1 ? ob + 1 : 0) * 256;
    float acc0 = 0.f, acc1 = 0.f;
    #pragma unroll
    for (int kc = 0; kc < 256; kc += 8) {
        const int kq = kc >> 2;
        const float4 v0 = a4[l * 64 + ((kq)     ^ (l & 7))];
        const float4 v1 = a4[l * 64 + ((kq + 1) ^ (l & 7))];
        const float av[8] = {v0.x, v0.y, v0.z, v0.w, v1.x, v1.y, v1.z, v1.w};
        #pragma unroll
        for (int kk = 0; kk < 8; ++kk) {
            acc0 = fmaf(w2a[kc + kk], av[kk], acc0);
            acc1 = fmaf(w2b[kc + kk], av[kk], acc1);
        }
    }
    float2 o;
    o.x = val0 ? (acc0 + b2[ob])     : 0.f;      // pad cols -> exact 0
    o.y = val1 ? (acc1 + b2[ob + 1]) : 0.f;
    *reinterpret_cast<float2*>(wso + TS_OFF + (rb * 64 + l) * 128 + ob) = o;
}

// ===== k5: out[b,o] = sum_k ts[b, oidx[b,o,k]]  (b2 folded; ts[126]=0) =====
__global__ __launch_bounds__(128) void k_gather(
    const float* __restrict__ ws, const int* __restrict__ oidx, float* __restrict__ out)
{
    const int b = blockIdx.x, t = threadIdx.x;
    if (t < NOUT) {
        const int base = b * NOUT * KIX + t * KIX;
        const int j0 = oidx[base], j1 = oidx[base + 1], j2 = oidx[base + 2];
        const float* ts = ws + TS_OFF + b * 128;
        out[b * NOUT + t] = ts[j0] + ts[j1] + ts[j2];
    }
}

extern "C" void kernel_launch(void* const* d_in, const int* in_sizes, int n_in,
                              void* d_out, int out_size, void* d_ws, size_t ws_size,
                              hipStream_t stream) {
    const float* x   = (const float*)d_in[0];
    const float* W0  = (const float*)d_in[1];
    const float* b0  = (const float*)d_in[2];
    const float* W1  = (const float*)d_in[3];
    const float* b1  = (const float*)d_in[4];
    const float* W2  = (const float*)d_in[5];
    const float* b2  = (const float*)d_in[6];
    const int*  iidx = (const int*)d_in[7];
    const int*  oidx = (const int*)d_in[8];
    float* out = (float*)d_out;
    float* ws  = (float*)d_ws;

    k_scatter<<<256,  512, 0, stream>>>(x, iidx, W0, ws);
    k_l0     <<<256,  256, 0, stream>>>(ws, b0, ws);
    k_l1     <<<256,  256, 0, stream>>>(ws, W1, b1, ws);
    k_l2     <<<256,  256, 0, stream>>>(ws, W2, b2, ws);
    k_gather <<<1024, 128, 0, stream>>>(ws, oidx, out);
}

// Round 12
// 29.972 us; speedup vs baseline: 1.3217x; 1.3217x over previous
//
#include <hip/hip_runtime.h>

typedef __attribute__((ext_vector_type(8))) short bf16x8;
typedef __attribute__((ext_vector_type(4))) float f32x4;

#define NIN  126
#define NOUT 126
#define KIX  3

// ushort-element offsets inside d_ws
#define XH_OFF   0u          // [1024][128] x scattered, hi
#define XL_OFF   131072u     // lo
#define W0H_OFF  262144u     // [256][128] W0 padded (cols>=126 zero)
#define W0L_OFF  294912u
#define W1H_OFF  327680u     // [256][256]
#define W1L_OFF  393216u
#define W2H_OFF  458752u     // [128][256] W2 padded (rows>=126 zero)
#define W2L_OFF  491520u
#define H1H_OFF  524288u     // [1024][256]
#define H1L_OFF  786432u
#define H2H_OFF  1048576u    // [1024][256]
#define H2L_OFF  1310720u
#define TS_BYTE_OFF (4u*1024u*1024u)   // float [1024][128] at byte 4MB

__device__ __forceinline__ float elu1(float v) { return v > 0.f ? v : expm1f(v); }

__device__ __forceinline__ unsigned short f2bf(float f) {
    unsigned u = __float_as_uint(f);
    u = (u + 0x7FFFu + ((u >> 16) & 1u)) >> 16;
    return (unsigned short)u;
}
__device__ __forceinline__ void split_bf(float v, unsigned short& h, unsigned short& l) {
    h = f2bf(v);
    const float hf = __uint_as_float(((unsigned)h) << 16);
    l = f2bf(v - hf);
}
__device__ __forceinline__ bf16x8 ldfrag(const unsigned short* p) {
    return *reinterpret_cast<const bf16x8*>(p);
}
__device__ __forceinline__ f32x4 mfma16(bf16x8 a, bf16x8 b, f32x4 c) {
    return __builtin_amdgcn_mfma_f32_16x16x32_bf16(a, b, c, 0, 0, 0);
}

// ===== k0: weights -> bf16 hi/lo (with padding) =====
__global__ __launch_bounds__(256) void k_wconv(
    const float* __restrict__ W0, const float* __restrict__ W1,
    const float* __restrict__ W2, unsigned short* __restrict__ ws)
{
    const int t = blockIdx.x * 256 + threadIdx.x;    // grid 512 -> 131072
    unsigned short h, l;
    if (t < 32768) {                                  // W0p [256][128]
        const int o = t >> 7, j = t & 127;
        const float v = (j < NIN) ? W0[o * NIN + j] : 0.f;
        split_bf(v, h, l);
        ws[W0H_OFF + t] = h; ws[W0L_OFF + t] = l;
    } else if (t < 98304) {                           // W1 [256][256]
        const int e = t - 32768;
        split_bf(W1[e], h, l);
        ws[W1H_OFF + e] = h; ws[W1L_OFF + e] = l;
    } else if (t < 131072) {                          // W2p [128][256]
        const int e = t - 98304;
        const int r = e >> 8, c = e & 255;
        const float v = (r < NOUT) ? W2[r * 256 + c] : 0.f;
        split_bf(v, h, l);
        ws[W2H_OFF + e] = h; ws[W2L_OFF + e] = l;
    }
}

// ===== k1: scatter x by batch_in_index -> XH/XL [1024][128] =====
__global__ __launch_bounds__(512) void k_scatter(
    const float* __restrict__ x, const int* __restrict__ iidx,
    unsigned short* __restrict__ ws)
{
    __shared__ float xe[4][128];
    const int t = threadIdx.x, row0 = blockIdx.x * 4;
    ((float*)xe)[t] = 0.f;
    __syncthreads();
    #pragma unroll
    for (int u = 0; u < 3; ++u) {
        const int n = t + u * 512;
        if (n < 4 * NIN * KIX) {
            const int r = n / (NIN * KIX), m = n - r * (NIN * KIX);
            const int j = iidx[(row0 + r) * (NIN * KIX) + m];
            if (j < NIN) atomicAdd(&xe[r][j], x[(row0 + r) * NIN + m / KIX]);
        }
    }
    __syncthreads();
    const int r = t >> 7, j = t & 127;
    unsigned short h, l;
    split_bf(xe[r][j], h, l);
    ws[XH_OFF + (row0 + r) * 128 + j] = h;
    ws[XL_OFF + (row0 + r) * 128 + j] = l;
}

// ===== k2: h1 = elu(xe @ W0p^T + b0)   M=1024 N=256 K=128 =====
// grid 256 = 32 row-blocks x 8 col-blocks; 4 waves = 2x2 16x16 tiles
__global__ __launch_bounds__(256) void k_gemm1(
    const unsigned short* __restrict__ ws, const float* __restrict__ b0,
    unsigned short* __restrict__ wso)
{
    const int bm = blockIdx.x & 31, bn = blockIdx.x >> 5;
    const int wave = threadIdx.x >> 6, lane = threadIdx.x & 63;
    const int rt = wave >> 1, ct = wave & 1;
    const int lr = lane & 15, kq = lane >> 4;
    const int row = bm * 32 + rt * 16 + lr;     // A row this lane feeds
    const int col = bn * 32 + ct * 16 + lr;     // B col this lane feeds

    const unsigned short* AH = ws + XH_OFF  + row * 128 + kq * 8;
    const unsigned short* AL = ws + XL_OFF  + row * 128 + kq * 8;
    const unsigned short* WH = ws + W0H_OFF + col * 128 + kq * 8;
    const unsigned short* WL = ws + W0L_OFF + col * 128 + kq * 8;

    f32x4 acc = {0.f, 0.f, 0.f, 0.f};
    #pragma unroll
    for (int kb = 0; kb < 4; ++kb) {
        const int ko = kb * 32;
        const bf16x8 ah = ldfrag(AH + ko), al = ldfrag(AL + ko);
        const bf16x8 wh = ldfrag(WH + ko), wl = ldfrag(WL + ko);
        acc = mfma16(ah, wh, acc);
        acc = mfma16(al, wh, acc);
        acc = mfma16(ah, wl, acc);
    }
    // D: col = lane&15 (=our col), row = (lane>>4)*4 + i
    const float bias = b0[col];
    #pragma unroll
    for (int i = 0; i < 4; ++i) {
        const int R = bm * 32 + rt * 16 + kq * 4 + i;
        const float v = elu1(acc[i] + bias);
        unsigned short h, l;
        split_bf(v, h, l);
        wso[H1H_OFF + R * 256 + col] = h;
        wso[H1L_OFF + R * 256 + col] = l;
    }
}

// ===== k3: h2 = elu(h1 @ W1^T + b1)   M=1024 N=256 K=256 =====
__global__ __launch_bounds__(256) void k_gemm2(
    const unsigned short* __restrict__ ws, const float* __restrict__ b1,
    unsigned short* __restrict__ wso)
{
    const int bm = blockIdx.x & 31, bn = blockIdx.x >> 5;
    const int wave = threadIdx.x >> 6, lane = threadIdx.x & 63;
    const int rt = wave >> 1, ct = wave & 1;
    const int lr = lane & 15, kq = lane >> 4;
    const int row = bm * 32 + rt * 16 + lr;
    const int col = bn * 32 + ct * 16 + lr;

    const unsigned short* AH = ws + H1H_OFF + row * 256 + kq * 8;
    const unsigned short* AL = ws + H1L_OFF + row * 256 + kq * 8;
    const unsigned short* WH = ws + W1H_OFF + col * 256 + kq * 8;
    const unsigned short* WL = ws + W1L_OFF + col * 256 + kq * 8;

    f32x4 acc = {0.f, 0.f, 0.f, 0.f};
    #pragma unroll
    for (int kb = 0; kb < 8; ++kb) {
        const int ko = kb * 32;
        const bf16x8 ah = ldfrag(AH + ko), al = ldfrag(AL + ko);
        const bf16x8 wh = ldfrag(WH + ko), wl = ldfrag(WL + ko);
        acc = mfma16(ah, wh, acc);
        acc = mfma16(al, wh, acc);
        acc = mfma16(ah, wl, acc);
    }
    const float bias = b1[col];
    #pragma unroll
    for (int i = 0; i < 4; ++i) {
        const int R = bm * 32 + rt * 16 + kq * 4 + i;
        const float v = elu1(acc[i] + bias);
        unsigned short h, l;
        split_bf(v, h, l);
        wso[H2H_OFF + R * 256 + col] = h;
        wso[H2L_OFF + R * 256 + col] = l;
    }
}

// ===== k4: ts = h2 @ W2p^T + b2p   M=1024 N=128 K=256 (f32 out) =====
// grid 128 = 32 row-blocks x 4 col-blocks
__global__ __launch_bounds__(256) void k_gemm3(
    const unsigned short* __restrict__ ws, const float* __restrict__ b2,
    float* __restrict__ ts)
{
    const int bm = blockIdx.x & 31, bn = blockIdx.x >> 5;
    const int wave = threadIdx.x >> 6, lane = threadIdx.x & 63;
    const int rt = wave >> 1, ct = wave & 1;
    const int lr = lane & 15, kq = lane >> 4;
    const int row = bm * 32 + rt * 16 + lr;
    const int col = bn * 32 + ct * 16 + lr;      // < 128

    const unsigned short* AH = ws + H2H_OFF + row * 256 + kq * 8;
    const unsigned short* AL = ws + H2L_OFF + row * 256 + kq * 8;
    const unsigned short* WH = ws + W2H_OFF + col * 256 + kq * 8;
    const unsigned short* WL = ws + W2L_OFF + col * 256 + kq * 8;

    f32x4 acc = {0.f, 0.f, 0.f, 0.f};
    #pragma unroll
    for (int kb = 0; kb < 8; ++kb) {
        const int ko = kb * 32;
        const bf16x8 ah = ldfrag(AH + ko), al = ldfrag(AL + ko);
        const bf16x8 wh = ldfrag(WH + ko), wl = ldfrag(WL + ko);
        acc = mfma16(ah, wh, acc);
        acc = mfma16(al, wh, acc);
        acc = mfma16(ah, wl, acc);
    }
    const float bias = (col < NOUT) ? b2[col] : 0.f;   // pad cols stay exactly 0
    #pragma unroll
    for (int i = 0; i < 4; ++i) {
        const int R = bm * 32 + rt * 16 + kq * 4 + i;
        ts[R * 128 + col] = acc[i] + bias;
    }
}

// ===== k5: out[b,o] = sum_k ts[b, oidx[b,o,k]]  (b2 folded; ts[126..127]=0) =====
__global__ __launch_bounds__(128) void k_gather(
    const float* __restrict__ ts, const int* __restrict__ oidx,
    float* __restrict__ out)
{
    const int b = blockIdx.x, t = threadIdx.x;
    if (t < NOUT) {
        const int base = b * NOUT * KIX + t * KIX;
        const int j0 = oidx[base], j1 = oidx[base + 1], j2 = oidx[base + 2];
        const float* tsr = ts + b * 128;
        out[b * NOUT + t] = tsr[j0] + tsr[j1] + tsr[j2];
    }
}

extern "C" void kernel_launch(void* const* d_in, const int* in_sizes, int n_in,
                              void* d_out, int out_size, void* d_ws, size_t ws_size,
                              hipStream_t stream) {
    const float* x   = (const float*)d_in[0];
    const float* W0  = (const float*)d_in[1];
    const float* b0  = (const float*)d_in[2];
    const float* W1  = (const float*)d_in[3];
    const float* b1  = (const float*)d_in[4];
    const float* W2  = (const float*)d_in[5];
    const float* b2  = (const float*)d_in[6];
    const int*  iidx = (const int*)d_in[7];
    const int*  oidx = (const int*)d_in[8];
    float* out = (float*)d_out;
    unsigned short* ws = (unsigned short*)d_ws;
    float* ts = (float*)((char*)d_ws + TS_BYTE_OFF);

    k_wconv  <<<512,  256, 0, stream>>>(W0, W1, W2, ws);
    k_scatter<<<256,  512, 0, stream>>>(x, iidx, ws);
    k_gemm1  <<<256,  256, 0, stream>>>(ws, b0, ws);
    k_gemm2  <<<256,  256, 0, stream>>>(ws, b1, ws);
    k_gemm3  <<<128,  256, 0, stream>>>(ws, b2, ts);
    k_gather <<<1024, 128, 0, stream>>>(ts, oidx, out);
}

// Round 13
// 18.327 us; speedup vs baseline: 2.1615x; 1.6354x over previous
//
#include <hip/hip_runtime.h>

#define B_    1024
#define NIN_  126
#define NOUT_ 126
#define K_    3
#define H1_   256
#define H2_   256
#define RPB   4
#define TPB   512
#define W1S   276                 // LDS row stride for W1 (bf16 units), 4-aligned
#define SMEM_BYTES (256 * W1S * 2 + (RPB * 128 + RPB * H1_ + RPB * H2_ + RPB * 128) * 4)

__device__ __forceinline__ float elu1(float v) { return v > 0.f ? v : expm1f(v); }

template<int CTRL>
__device__ __forceinline__ float dpp_add(float v) {
    int s = __builtin_amdgcn_update_dpp(0, __float_as_int(v), CTRL, 0xF, 0xF, true);
    return v + __int_as_float(s);
}
// sum over 8 consecutive lanes: xor1,xor2 via DPP (VALU), xor4 via ds_swizzle
__device__ __forceinline__ float qsum8(float v) {
    v = dpp_add<0xB1>(v);
    v = dpp_add<0x4E>(v);
    int s = __builtin_amdgcn_ds_swizzle(__float_as_int(v), 0x101F);
    return v + __int_as_float(s);
}
// barrier draining only LDS ops; global loads stay in flight
__device__ __forceinline__ void barrier_lds() {
    asm volatile("s_waitcnt lgkmcnt(0)\n\ts_barrier" ::: "memory");
}
__device__ __forceinline__ unsigned f2bf(float f) {
    unsigned u = __float_as_uint(f);
    return (u + 0x7FFFu + ((u >> 16) & 1u)) >> 16;
}
__device__ __forceinline__ unsigned packbf(float a, float b) {
    return f2bf(a) | (f2bf(b) << 16);
}
__device__ __forceinline__ float2 bf2f(unsigned u) {
    return make_float2(__uint_as_float(u << 16), __uint_as_float(u & 0xFFFF0000u));
}

__global__ __launch_bounds__(TPB) void bim_fused(
    const float* __restrict__ x,  const float* __restrict__ W0,
    const float* __restrict__ b0, const float* __restrict__ W1,
    const float* __restrict__ b1, const float* __restrict__ W2,
    const float* __restrict__ b2, const int*  __restrict__ iidx,
    const int*  __restrict__ oidx, float* __restrict__ out)
{
    extern __shared__ char smem[];
    unsigned short* w1l = (unsigned short*)smem;             // [256][W1S] bf16
    float* xe  = (float*)(smem + 256 * W1S * 2);             // [4][128], cols 126/127 = 0
    float* h1s = xe  + RPB * 128;                            // [4][256]
    float* h2s = h1s + RPB * H1_;                            // [4][256]
    float* tsb = h2s + RPB * H2_;                            // [4][128], b2 folded

    const int tid  = threadIdx.x;
    const int row0 = blockIdx.x * RPB;
    const int q    = tid & 7;    // k-split lane
    const int g    = tid >> 3;   // group 0..63 -> 4 neurons

    const float4* w1f4 = reinterpret_cast<const float4*>(W1);   // 16384 float4

    // ---- phase-A operands (earliest consumers) ----
    int aj0, aj1, aj2, ar0, ar1, ar2; float ax0, ax1, ax2;
    {
        const int n0 = tid;
        ar0 = n0 / (NIN_ * K_); const int m0 = n0 - ar0 * (NIN_ * K_);
        aj0 = iidx[(row0 + ar0) * (NIN_ * K_) + m0];
        ax0 = x[(row0 + ar0) * NIN_ + m0 / K_];
        const int n1 = tid + TPB;                    // < 1512 always
        ar1 = n1 / (NIN_ * K_); const int m1 = n1 - ar1 * (NIN_ * K_);
        aj1 = iidx[(row0 + ar1) * (NIN_ * K_) + m1];
        ax1 = x[(row0 + ar1) * NIN_ + m1 / K_];
        const int n2 = tid + 2 * TPB;
        const int n2c = n2 < RPB * NIN_ * K_ ? n2 : 0;
        ar2 = n2c / (NIN_ * K_); const int m2 = n2c - ar2 * (NIN_ * K_);
        aj2 = iidx[(row0 + ar2) * (NIN_ * K_) + m2];
        ax2 = x[(row0 + ar2) * NIN_ + m2 / K_];
        if (n2 >= RPB * NIN_ * K_) aj2 = NIN_;
    }

    // ---- W0 in FULL f32 (64 VGPRs), consumed in B, covered by phase A ----
    const float* wb = W0 + (g * 4) * NIN_;
    float2 wA[4][4], wB[4][4];   // [jj][oo]
    #pragma unroll
    for (int jj = 0; jj < 4; ++jj) {
        const int j  = q * 4 + jj * 32;
        const int j2 = (j + 2 > NIN_ - 2) ? (NIN_ - 2) : (j + 2);  // xe pad=0 kills garbage
        #pragma unroll
        for (int oo = 0; oo < 4; ++oo) {
            wA[jj][oo] = *reinterpret_cast<const float2*>(wb + oo * NIN_ + j);
            wB[jj][oo] = *reinterpret_cast<const float2*>(wb + oo * NIN_ + j2);
        }
    }

    // ---- W1 staging chunk 0 (8 float4 = 32 VGPRs) ----
    float4 s0[8], s1[8], s2[8], s3[8];
#define ISSUE_CHUNK(S, P) { _Pragma("unroll") \
    for (int u = 0; u < 8; ++u) S[u] = w1f4[((P) * 8 + u) * TPB + tid]; }
#define WRITE_CHUNK(S, P) { _Pragma("unroll") \
    for (int u = 0; u < 8; ++u) { \
        const int i4 = ((P) * 8 + u) * TPB + tid; \
        const int row = i4 >> 6, c4 = i4 & 63; \
        uint2 pk; pk.x = packbf(S[u].x, S[u].y); pk.y = packbf(S[u].z, S[u].w); \
        *reinterpret_cast<uint2*>(&w1l[row * W1S + c4 * 4]) = pk; } }

    ISSUE_CHUNK(s0, 0)

    // ---- phase-E indices + biases (small) ----
    int ej0, ej1, ej2;
    {
        const int t = tid < RPB * NOUT_ ? tid : 0;
        const int r = t / NOUT_, o = t - r * NOUT_;
        const int base = (row0 + r) * (NOUT_ * K_) + o * K_;
        ej0 = oidx[base]; ej1 = oidx[base + 1]; ej2 = oidx[base + 2];
    }
    const float4 b0v = *reinterpret_cast<const float4*>(b0 + g * 4);
    const float4 b1v = *reinterpret_cast<const float4*>(b1 + g * 4);
    const int    gD  = (g < 63) ? g : 0;
    const float2 b2v = *reinterpret_cast<const float2*>(b2 + gD * 2);

    // ======== phase A: zero xe, barrier, scatter; stage chunks 0,1 ========
    xe[tid] = 0.0f;                            // 512 = 4*128
    barrier_lds();
    if (aj0 < NIN_) atomicAdd(&xe[ar0 * 128 + aj0], ax0);
    if (aj1 < NIN_) atomicAdd(&xe[ar1 * 128 + aj1], ax1);
    if (aj2 < NIN_) atomicAdd(&xe[ar2 * 128 + aj2], ax2);
    WRITE_CHUNK(s0, 0)
    ISSUE_CHUNK(s1, 1)
    barrier_lds();

    // FMA step macros (compile-time indices)
#define BSTEP(JJ) { \
        const int j = q * 4 + (JJ) * 32; \
        _Pragma("unroll") \
        for (int r = 0; r < RPB; ++r) { \
            const float4 a = *reinterpret_cast<const float4*>(&xe[r * 128 + j]); \
            _Pragma("unroll") \
            for (int oo = 0; oo < 4; ++oo) { \
                acc[oo][r] = fmaf(wA[JJ][oo].x, a.x, acc[oo][r]); \
                acc[oo][r] = fmaf(wA[JJ][oo].y, a.y, acc[oo][r]); \
                acc[oo][r] = fmaf(wB[JJ][oo].x, a.z, acc[oo][r]); \
                acc[oo][r] = fmaf(wB[JJ][oo].y, a.w, acc[oo][r]); \
            } } }
#define CSTEP(JJ) { \
        const int j = q * 4 + (JJ) * 32; \
        float4 a[RPB]; \
        _Pragma("unroll") \
        for (int r = 0; r < RPB; ++r) \
            a[r] = *reinterpret_cast<const float4*>(&h1s[r * H1_ + j]); \
        _Pragma("unroll") \
        for (int oo = 0; oo < 4; ++oo) { \
            const uint2 wv = *reinterpret_cast<const uint2*>(&w1l[(g * 4 + oo) * W1S + j]); \
            const float2 p0 = bf2f(wv.x), p1 = bf2f(wv.y); \
            _Pragma("unroll") \
            for (int r = 0; r < RPB; ++r) { \
                acc[oo][r] = fmaf(p0.x, a[r].x, acc[oo][r]); \
                acc[oo][r] = fmaf(p0.y, a[r].y, acc[oo][r]); \
                acc[oo][r] = fmaf(p1.x, a[r].z, acc[oo][r]); \
                acc[oo][r] = fmaf(p1.y, a[r].w, acc[oo][r]); \
            } } }
#define DSTEP(JJ) { \
        const int j = q * 4 + (JJ) * 32; \
        float4 a[RPB]; \
        _Pragma("unroll") \
        for (int r = 0; r < RPB; ++r) \
            a[r] = *reinterpret_cast<const float4*>(&h2s[r * H2_ + j]); \
        _Pragma("unroll") \
        for (int oo = 0; oo < 2; ++oo) { \
            _Pragma("unroll") \
            for (int r = 0; r < RPB; ++r) { \
                accd[oo][r] = fmaf(wd[JJ][oo].x, a[r].x, accd[oo][r]); \
                accd[oo][r] = fmaf(wd[JJ][oo].y, a[r].y, accd[oo][r]); \
                accd[oo][r] = fmaf(wd[JJ][oo].z, a[r].z, accd[oo][r]); \
                accd[oo][r] = fmaf(wd[JJ][oo].w, a[r].w, accd[oo][r]); \
            } } }

    // ======== phase B: h1 = elu(xe @ W0^T + b0); stage chunks 1..3 ========
    {
        float acc[4][4] = {};   // [oo][r]
        BSTEP(0)
        BSTEP(1)
        WRITE_CHUNK(s1, 1)
        ISSUE_CHUNK(s2, 2)
        BSTEP(2)
        BSTEP(3)
        WRITE_CHUNK(s2, 2)
        ISSUE_CHUNK(s3, 3)
        #pragma unroll
        for (int oo = 0; oo < 4; ++oo)
            #pragma unroll
            for (int r = 0; r < RPB; ++r) acc[oo][r] = qsum8(acc[oo][r]);
        // lane q writes flat accs 2q, 2q+1 (flat = oo*4 + r)
        float v0 = acc[0][0], v1 = acc[0][1];
        #pragma unroll
        for (int i = 1; i < 8; ++i) {
            v0 = (q == i) ? acc[(2 * i) >> 2][(2 * i) & 3]         : v0;
            v1 = (q == i) ? acc[(2 * i + 1) >> 2][(2 * i + 1) & 3] : v1;
        }
        const int oo = q >> 1, r0 = (q & 1) * 2;
        const float bias = (oo == 0) ? b0v.x : (oo == 1) ? b0v.y : (oo == 2) ? b0v.z : b0v.w;
        const int o = g * 4 + oo;
        h1s[r0 * H1_ + o]       = elu1(v0 + bias);
        h1s[(r0 + 1) * H1_ + o] = elu1(v1 + bias);
        WRITE_CHUNK(s3, 3)
    }
    // ---- issue W2 in FULL f32 (64 VGPRs; W0/staging regs dead) ----
    const float* wdp = W2 + (gD * 2) * H2_ + q * 4;
    float4 wd[8][2];
    #pragma unroll
    for (int jj = 0; jj < 8; ++jj)
        #pragma unroll
        for (int oo = 0; oo < 2; ++oo)
            wd[jj][oo] = *reinterpret_cast<const float4*>(wdp + oo * H2_ + jj * 32);
    barrier_lds();   // h1s + all w1l writes visible

    // ======== phase C: h2 = elu(h1 @ W1lds^T + b1) ========
    {
        float acc[4][4] = {};
        CSTEP(0) CSTEP(1) CSTEP(2) CSTEP(3)
        CSTEP(4) CSTEP(5) CSTEP(6) CSTEP(7)
        #pragma unroll
        for (int oo = 0; oo < 4; ++oo)
            #pragma unroll
            for (int r = 0; r < RPB; ++r) acc[oo][r] = qsum8(acc[oo][r]);
        float v0 = acc[0][0], v1 = acc[0][1];
        #pragma unroll
        for (int i = 1; i < 8; ++i) {
            v0 = (q == i) ? acc[(2 * i) >> 2][(2 * i) & 3]         : v0;
            v1 = (q == i) ? acc[(2 * i + 1) >> 2][(2 * i + 1) & 3] : v1;
        }
        const int oo = q >> 1, r0 = (q & 1) * 2;
        const float bias = (oo == 0) ? b1v.x : (oo == 1) ? b1v.y : (oo == 2) ? b1v.z : b1v.w;
        const int o = g * 4 + oo;
        h2s[r0 * H2_ + o]       = elu1(v0 + bias);
        h2s[(r0 + 1) * H2_ + o] = elu1(v1 + bias);
    }
    barrier_lds();

    // ======== phase D: ts[r][j] = h2s[r].W2[j,:] + b2[j] ========
    {
        float accd[2][4] = {};
        DSTEP(0) DSTEP(1) DSTEP(2) DSTEP(3)
        DSTEP(4) DSTEP(5) DSTEP(6) DSTEP(7)
        #pragma unroll
        for (int oo = 0; oo < 2; ++oo)
            #pragma unroll
            for (int r = 0; r < RPB; ++r) accd[oo][r] = qsum8(accd[oo][r]);
        float v = accd[0][0];
        #pragma unroll
        for (int i = 1; i < 8; ++i) v = (q == i) ? accd[i >> 2][i & 3] : v;
        const int oo = q >> 2, rr = q & 3;
        if (g < 63) tsb[rr * 128 + g * 2 + oo] = v + (oo ? b2v.y : b2v.x);
        else        tsb[rr * 128 + 126 + oo]   = 0.0f;
    }
    barrier_lds();

    // ======== phase E: out[b,o] = sum_k tsb[r][ej_k] (b2 folded) ========
    if (tid < RPB * NOUT_) {
        const int r = tid / NOUT_, o = tid - r * NOUT_;
        out[(row0 + r) * NOUT_ + o] = tsb[r * 128 + ej0] + tsb[r * 128 + ej1] + tsb[r * 128 + ej2];
    }
#undef BSTEP
#undef CSTEP
#undef DSTEP
#undef ISSUE_CHUNK
#undef WRITE_CHUNK
}

extern "C" void kernel_launch(void* const* d_in, const int* in_sizes, int n_in,
                              void* d_out, int out_size, void* d_ws, size_t ws_size,
                              hipStream_t stream) {
    const float* x   = (const float*)d_in[0];
    const float* W0  = (const float*)d_in[1];
    const float* b0  = (const float*)d_in[2];
    const float* W1  = (const float*)d_in[3];
    const float* b1  = (const float*)d_in[4];
    const float* W2  = (const float*)d_in[5];
    const float* b2  = (const float*)d_in[6];
    const int*  iidx = (const int*)d_in[7];
    const int*  oidx = (const int*)d_in[8];
    float* out = (float*)d_out;

    bim_fused<<<B_ / RPB, TPB, SMEM_BYTES, stream>>>(
        x, W0, b0, W1, b1, W2, b2, iidx, oidx, out);
}